// Round 5
// baseline (1350.166 us; speedup 1.0000x reference)
//
#include <hip/hip_runtime.h>
#include <hip/hip_fp16.h>
#include <math.h>

#define N_NODES 100000
#define N_EDGES 1600000
#define FIN 256
#define NBLK_NODES 391   // ceil(100000/256)
#define NBUCK 782        // ceil(100000/128), 128 nodes per bucket

typedef _Float16 h8 __attribute__((ext_vector_type(8)));
typedef float f4 __attribute__((ext_vector_type(4)));

// ---------------- degree (int) ----------------
__global__ __launch_bounds__(256) void k_count_deg(const int* __restrict__ dst, int* __restrict__ degi) {
    int e = blockIdx.x * 256 + threadIdx.x;
    if (e < N_EDGES) atomicAdd(&degi[dst[e]], 1);
}

__global__ __launch_bounds__(256) void k_dinv(const int* __restrict__ degi, float* __restrict__ dinv) {
    int i = blockIdx.x * 256 + threadIdx.x;
    if (i < N_NODES) dinv[i] = rsqrtf((float)degi[i] + 1.0f);  // +1 = self loop
}

// ---------------- W1 -> f16 MFMA B-fragment layout ----------------
__global__ __launch_bounds__(256) void k_prepW1(const float* __restrict__ W1, _Float16* __restrict__ Bfrag) {
    int i = blockIdx.x * 256 + threadIdx.x;   // 0..16383
    int j = i & 7, lane = (i >> 3) & 63, nt = (i >> 9) & 3, ks = i >> 11;
    int k = ks * 32 + ((lane >> 4) << 3) + j;
    int c = nt * 16 + (lane & 15);
    Bfrag[i] = (_Float16)W1[k * 64 + c];
}

// ---------------- bucket counts: sum degi over 128-node chunks ----------------
__global__ __launch_bounds__(128) void k_bucket_cnt(const int* __restrict__ degi, int* __restrict__ bcnt) {
    __shared__ int sd[128];
    int t = threadIdx.x;
    int n = blockIdx.x * 128 + t;
    sd[t] = (n < N_NODES) ? degi[n] : 0;
    __syncthreads();
    for (int s = 64; s > 0; s >>= 1) {
        if (t < s) sd[t] += sd[t + s];
        __syncthreads();
    }
    if (t == 0) bcnt[blockIdx.x] = sd[0];
}

// ---------------- exclusive scan of 782 bucket counts (single block) ----------------
__global__ __launch_bounds__(1024) void k_scan_buckets(const int* __restrict__ bcnt, int* __restrict__ bbase) {
    __shared__ int sd[1024];
    int t = threadIdx.x;
    int v = (t < NBUCK) ? bcnt[t] : 0;
    sd[t] = v;
    __syncthreads();
    for (int off = 1; off < 1024; off <<= 1) {
        int tv = (t >= off) ? sd[t - off] : 0;
        __syncthreads();
        sd[t] += tv;
        __syncthreads();
    }
    if (t < NBUCK) bbase[t] = sd[t] - v;
    if (t == NBUCK - 1) bbase[NBUCK] = sd[t];
}

// ---------------- bin edges: bpack = {src, (local_dst<<16)|f16(norm)} ----------------
__global__ __launch_bounds__(256) void k_fill_bins(const int* __restrict__ src, const int* __restrict__ dst,
                                                   const float* __restrict__ dinv,
                                                   const int* __restrict__ bbase, int* __restrict__ bcur,
                                                   int2* __restrict__ bpack) {
    int e = blockIdx.x * 256 + threadIdx.x;
    if (e >= N_EDGES) return;
    int s = src[e], d = dst[e];
    int b = d >> 7, ld = d & 127;
    float nrm = dinv[s] * dinv[d];
    int pos = bbase[b] + atomicAdd(&bcur[b], 1);
    unsigned short nh = __half_as_ushort(__float2half_rn(nrm));
    bpack[pos] = make_int2(s, (ld << 16) | (int)nh);
}

// ---------------- GEMM1 via MFMA: h = x @ W1, f16 out ----------------
__global__ __launch_bounds__(256) void k_gemm1(const float* __restrict__ x,
                                               const _Float16* __restrict__ Bfrag,
                                               __half* __restrict__ hh) {
    const int tid = threadIdx.x;
    const int wave = tid >> 6, lane = tid & 63;
    const int lrow = lane & 15;
    const int lk = lane >> 4;
    const int row = blockIdx.x * 64 + wave * 16 + lrow;
    const int rowc = (row < N_NODES) ? row : (N_NODES - 1);
    const float* xp = x + (size_t)rowc * 256 + lk * 8;
    const h8* bp = (const h8*)Bfrag + lane;

    f4 acc0 = {0.f, 0.f, 0.f, 0.f};
    f4 acc1 = {0.f, 0.f, 0.f, 0.f};
    f4 acc2 = {0.f, 0.f, 0.f, 0.f};
    f4 acc3 = {0.f, 0.f, 0.f, 0.f};

    #pragma unroll 2
    for (int ks = 0; ks < 8; ++ks) {
        float4 a01 = *(const float4*)(xp + ks * 32);
        float4 a23 = *(const float4*)(xp + ks * 32 + 4);
        h8 af;
        af[0] = (_Float16)a01.x; af[1] = (_Float16)a01.y;
        af[2] = (_Float16)a01.z; af[3] = (_Float16)a01.w;
        af[4] = (_Float16)a23.x; af[5] = (_Float16)a23.y;
        af[6] = (_Float16)a23.z; af[7] = (_Float16)a23.w;
        h8 b0 = bp[(ks * 4 + 0) * 64];
        h8 b1 = bp[(ks * 4 + 1) * 64];
        h8 b2 = bp[(ks * 4 + 2) * 64];
        h8 b3 = bp[(ks * 4 + 3) * 64];
        acc0 = __builtin_amdgcn_mfma_f32_16x16x32_f16(af, b0, acc0, 0, 0, 0);
        acc1 = __builtin_amdgcn_mfma_f32_16x16x32_f16(af, b1, acc1, 0, 0, 0);
        acc2 = __builtin_amdgcn_mfma_f32_16x16x32_f16(af, b2, acc2, 0, 0, 0);
        acc3 = __builtin_amdgcn_mfma_f32_16x16x32_f16(af, b3, acc3, 0, 0, 0);
    }

    const int orow0 = blockIdx.x * 64 + wave * 16 + lk * 4;
    const bool evlane = ((lane & 1) == 0);
#define STORE_TILE(ACC, NT) { \
    _Pragma("unroll") \
    for (int r = 0; r < 4; ++r) { \
        float v = ACC[r]; \
        float o = __shfl_xor(v, 1); \
        int orow = orow0 + r; \
        if (evlane && orow < N_NODES) \
            *(__half2*)&hh[(size_t)orow * 64 + (NT) * 16 + lrow] = __floats2half2_rn(v, o); \
    } }
    STORE_TILE(acc0, 0)
    STORE_TILE(acc1, 1)
    STORE_TILE(acc2, 2)
    STORE_TILE(acc3, 3)
#undef STORE_TILE
}

// ---------------- bucket agg1 + self-loop + b1 + relu + GEMM2 ----------------
// one block per 128-node bucket; LDS f32 accumulator with pair-swizzled cols:
// channel c stored at col ((c&1)<<5)|(c>>1), row padded to 65 -> conflict-free ds_add + epilogue reads
__global__ __launch_bounds__(256) void k_agg1_gemm2(const int* __restrict__ bbase,
                                                    const int2* __restrict__ bpack,
                                                    const float* __restrict__ dinv,
                                                    const __half* __restrict__ hh,
                                                    const float* __restrict__ b1,
                                                    const float* __restrict__ W2,
                                                    __half* __restrict__ h2h) {
    __shared__ float accs[128][65];
    __shared__ float W2s[64][17];
    const int tid = threadIdx.x;
    for (int i = tid; i < 128 * 65; i += 256) ((float*)accs)[i] = 0.f;
    for (int i = tid; i < 64 * 16; i += 256) W2s[i >> 4][i & 15] = W2[i];
    __syncthreads();

    const int wave = tid >> 6, lane = tid & 63;
    const int half_id = lane >> 5, l = lane & 31;   // channels 2l, 2l+1 -> cols l, 32+l
    const int s0 = bbase[blockIdx.x], s1 = bbase[blockIdx.x + 1];

#define EDGE1(P) { \
    int lds = (P).y >> 16; \
    float w = __half2float(__ushort_as_half((unsigned short)((P).y & 0xffff))); \
    float2 f = __half22float2(*(const __half2*)(hh + (size_t)(P).x * 64 + 2 * l)); \
    atomicAdd(&accs[lds][l],      f.x * w); \
    atomicAdd(&accs[lds][32 + l], f.y * w); }

    int i = s0 + wave * 2 + half_id;
    for (; i + 24 < s1; i += 32) {
        int2 p0 = bpack[i], p1 = bpack[i + 8], p2 = bpack[i + 16], p3 = bpack[i + 24];
        EDGE1(p0) EDGE1(p1) EDGE1(p2) EDGE1(p3)
    }
    for (; i < s1; i += 8) {
        int2 p = bpack[i];
        EDGE1(p)
    }
#undef EDGE1
    __syncthreads();

    const int node0 = blockIdx.x * 128;
    // fold self-loop + b1 + relu (in place, swizzled)
    for (int idx = tid; idx < 128 * 64; idx += 256) {
        int ld = idx >> 6, c = idx & 63;
        int node = node0 + ld;
        if (node < N_NODES) {
            float di = dinv[node];
            float sv = __half2float(hh[(size_t)node * 64 + c]);
            int col = ((c & 1) << 5) | (c >> 1);
            float v = accs[ld][col] + sv * di * di + b1[c];
            accs[ld][col] = fmaxf(v, 0.f);
        }
    }
    __syncthreads();

    // GEMM2: 2 threads per node, 8 output channels each
    const int n = tid >> 1, sec = tid & 1;
    const int node = node0 + n;
    if (node < N_NODES) {
        float o[8] = {0.f, 0.f, 0.f, 0.f, 0.f, 0.f, 0.f, 0.f};
        #pragma unroll
        for (int k = 0; k < 64; ++k) {
            float h1 = accs[n][((k & 1) << 5) | (k >> 1)];
            #pragma unroll
            for (int j = 0; j < 8; ++j) o[j] = fmaf(h1, W2s[k][sec * 8 + j], o[j]);
        }
        __half2 q[4];
        #pragma unroll
        for (int j = 0; j < 4; ++j) q[j] = __floats2half2_rn(o[2 * j], o[2 * j + 1]);
        *(int4*)(h2h + (size_t)node * 16 + sec * 8) = *(int4*)q;
    }
}

// ---------------- bucket agg2 + self-loop + b2 + log_softmax ----------------
// channel c stored at col ((c&1)<<3)|(c>>1), rows padded to 17
__global__ __launch_bounds__(256) void k_agg2_final(const int* __restrict__ bbase,
                                                    const int2* __restrict__ bpack,
                                                    const float* __restrict__ dinv,
                                                    const __half* __restrict__ h2h,
                                                    const float* __restrict__ b2,
                                                    float* __restrict__ out) {
    __shared__ float acc2[128][17];
    const int tid = threadIdx.x;
    for (int i = tid; i < 128 * 17; i += 256) ((float*)acc2)[i] = 0.f;
    __syncthreads();

    const int wave = tid >> 6, lane = tid & 63;
    const int g = lane >> 3, cp = lane & 7;   // channels 2cp, 2cp+1 -> cols cp, 8+cp
    const int s0 = bbase[blockIdx.x], s1 = bbase[blockIdx.x + 1];

#define EDGE2(P) { \
    int lds = (P).y >> 16; \
    float w = __half2float(__ushort_as_half((unsigned short)((P).y & 0xffff))); \
    float2 f = __half22float2(*(const __half2*)(h2h + (size_t)(P).x * 16 + 2 * cp)); \
    atomicAdd(&acc2[lds][cp],     f.x * w); \
    atomicAdd(&acc2[lds][8 + cp], f.y * w); }

    int i = s0 + wave * 8 + g;
    for (; i + 32 < s1; i += 64) {
        int2 p0 = bpack[i], p1 = bpack[i + 32];
        EDGE2(p0) EDGE2(p1)
    }
    for (; i < s1; i += 32) {
        int2 p = bpack[i];
        EDGE2(p)
    }
#undef EDGE2
    __syncthreads();

    const int node0 = blockIdx.x * 128;
    const int n = tid >> 1, sec = tid & 1;
    const int node = node0 + n;
    if (node >= N_NODES) return;
    const float di = dinv[node];
    const float dii = di * di;
    float z[8];
    #pragma unroll
    for (int j = 0; j < 8; ++j) {
        int c = sec * 8 + j;
        int col = ((c & 1) << 3) | (c >> 1);
        z[j] = acc2[n][col] + __half2float(h2h[(size_t)node * 16 + c]) * dii + b2[c];
    }
    float m = z[0];
    #pragma unroll
    for (int j = 1; j < 8; ++j) m = fmaxf(m, z[j]);
    m = fmaxf(m, __shfl_xor(m, 1));
    float s = 0.f;
    #pragma unroll
    for (int j = 0; j < 8; ++j) s += __expf(z[j] - m);
    s += __shfl_xor(s, 1);
    float ls = logf(s);
    float4 o0 = {z[0] - m - ls, z[1] - m - ls, z[2] - m - ls, z[3] - m - ls};
    float4 o1 = {z[4] - m - ls, z[5] - m - ls, z[6] - m - ls, z[7] - m - ls};
    *(float4*)(out + (size_t)node * 16 + sec * 8) = o0;
    *(float4*)(out + (size_t)node * 16 + sec * 8 + 4) = o1;
}

extern "C" void kernel_launch(void* const* d_in, const int* in_sizes, int n_in,
                              void* d_out, int out_size, void* d_ws, size_t ws_size,
                              hipStream_t stream) {
    const float* x  = (const float*)d_in[0];
    const int* ei   = (const int*)d_in[1];
    const float* W1 = (const float*)d_in[2];
    const float* b1 = (const float*)d_in[3];
    const float* W2 = (const float*)d_in[4];
    const float* b2 = (const float*)d_in[5];
    const int* src = ei;
    const int* dst = ei + N_EDGES;

    // workspace layout (int units; bpack 8B-aligned: 210540 ints before it, even)
    _Float16* Bfrag = (_Float16*)d_ws;                   // 16384 halves = 8192 ints
    int*    degi    = (int*)d_ws + 8192;                 // N
    int*    bcur    = degi + N_NODES;                    // NBUCK (memset with degi)
    float*  dinv    = (float*)(bcur + NBUCK);            // N
    int*    bcnt    = (int*)(dinv + N_NODES);            // NBUCK
    int*    bbase   = bcnt + NBUCK;                      // NBUCK+1
    int*    padp    = bbase + NBUCK + 1;                 // +1 pad -> even
    int2*   bpack   = (int2*)(padp + 1);                 // E int2
    __half* hh      = (__half*)(bpack + N_EDGES);        // N*64 half
    __half* h2h     = hh + (size_t)N_NODES * 64;         // N*16 half
    float*  out     = (float*)d_out;

    hipMemsetAsync(degi, 0, (N_NODES + NBUCK) * sizeof(int), stream);

    k_count_deg<<<(N_EDGES + 255) / 256, 256, 0, stream>>>(dst, degi);
    k_dinv<<<NBLK_NODES, 256, 0, stream>>>(degi, dinv);
    k_prepW1<<<64, 256, 0, stream>>>(W1, Bfrag);
    k_bucket_cnt<<<NBUCK, 128, 0, stream>>>(degi, bcnt);
    k_scan_buckets<<<1, 1024, 0, stream>>>(bcnt, bbase);
    k_fill_bins<<<(N_EDGES + 255) / 256, 256, 0, stream>>>(src, dst, dinv, bbase, bcur, bpack);
    k_gemm1<<<(N_NODES + 63) / 64, 256, 0, stream>>>(x, Bfrag, hh);
    k_agg1_gemm2<<<NBUCK, 256, 0, stream>>>(bbase, bpack, dinv, hh, b1, W2, h2h);
    k_agg2_final<<<NBUCK, 256, 0, stream>>>(bbase, bpack, dinv, h2h, b2, out);
}

// Round 6
// 267.112 us; speedup vs baseline: 5.0547x; 5.0547x over previous
//
#include <hip/hip_runtime.h>
#include <hip/hip_fp16.h>
#include <math.h>

#define N_NODES 100000
#define N_EDGES 1600000
#define FIN 256
#define NBLK_NODES 391   // ceil(100000/256)
#define NB 196           // ceil(100000/512): 512-node dst buckets

typedef _Float16 h8 __attribute__((ext_vector_type(8)));
typedef float f4 __attribute__((ext_vector_type(4)));

// ---------------- degree (int) ----------------
__global__ __launch_bounds__(256) void k_count_deg(const int* __restrict__ dst, int* __restrict__ degi) {
    int e = blockIdx.x * 256 + threadIdx.x;
    if (e < N_EDGES) atomicAdd(&degi[dst[e]], 1);
}

__global__ __launch_bounds__(256) void k_dinv(const int* __restrict__ degi, float* __restrict__ dinv) {
    int i = blockIdx.x * 256 + threadIdx.x;
    if (i < N_NODES) dinv[i] = rsqrtf((float)degi[i] + 1.0f);  // +1 = self loop
}

// ---------------- W1 -> f16 MFMA B-fragment layout ----------------
__global__ __launch_bounds__(256) void k_prepW1(const float* __restrict__ W1, _Float16* __restrict__ Bfrag) {
    int i = blockIdx.x * 256 + threadIdx.x;   // 0..16383
    int j = i & 7, lane = (i >> 3) & 63, nt = (i >> 9) & 3, ks = i >> 11;
    int k = ks * 32 + ((lane >> 4) << 3) + j;
    int c = nt * 16 + (lane & 15);
    Bfrag[i] = (_Float16)W1[k * 64 + c];
}

// ---------------- CSR offsets: 2-level exclusive scan ----------------
__global__ __launch_bounds__(256) void k_block_sum(const int* __restrict__ degi, int* __restrict__ bsums) {
    __shared__ int sd[256];
    int tid = threadIdx.x;
    int i = blockIdx.x * 256 + tid;
    sd[tid] = (i < N_NODES) ? degi[i] : 0;
    __syncthreads();
    for (int s = 128; s > 0; s >>= 1) {
        if (tid < s) sd[tid] += sd[tid + s];
        __syncthreads();
    }
    if (tid == 0) bsums[blockIdx.x] = sd[0];
}

__global__ __launch_bounds__(512) void k_scan_bsums(int* __restrict__ bsums, int nb) {
    __shared__ int sd[512];
    int tid = threadIdx.x;
    int v = (tid < nb) ? bsums[tid] : 0;
    sd[tid] = v;
    __syncthreads();
    for (int off = 1; off < 512; off <<= 1) {
        int t = (tid >= off) ? sd[tid - off] : 0;
        __syncthreads();
        sd[tid] += t;
        __syncthreads();
    }
    if (tid < nb) bsums[tid] = sd[tid] - v;  // exclusive
}

__global__ __launch_bounds__(256) void k_scan_block(const int* __restrict__ degi,
                                                   const int* __restrict__ bsums,
                                                   int* __restrict__ offsets) {
    __shared__ int sd[256];
    int tid = threadIdx.x;
    int i = blockIdx.x * 256 + tid;
    int v = (i < N_NODES) ? degi[i] : 0;
    sd[tid] = v;
    __syncthreads();
    for (int off = 1; off < 256; off <<= 1) {
        int t = (tid >= off) ? sd[tid - off] : 0;
        __syncthreads();
        sd[tid] += t;
        __syncthreads();
    }
    if (i < N_NODES) offsets[i] = bsums[blockIdx.x] + sd[tid] - v;
    if (i == N_NODES - 1) offsets[N_NODES] = bsums[blockIdx.x] + sd[tid];
}

__global__ __launch_bounds__(256) void k_init_bcur(const int* __restrict__ offsets, int* __restrict__ bcur) {
    int t = threadIdx.x;
    if (t < NB) bcur[t] = offsets[t << 9];
}

// ---------------- pass A: bin edges into 512-node buckets ----------------
// per-block LDS histogram -> one global reserve atomic per bucket -> contiguous appends
__global__ __launch_bounds__(256) void k_fill_bins(const int* __restrict__ src, const int* __restrict__ dst,
                                                   const float* __restrict__ dinv,
                                                   int* __restrict__ bcur, int2* __restrict__ bpack) {
    __shared__ int hist[NB], curs[NB], bstart[NB];
    const int tid = threadIdx.x;
    for (int i = tid; i < NB; i += 256) { hist[i] = 0; curs[i] = 0; }
    __syncthreads();
    const int base = blockIdx.x * 4096;
    int eb[16]; int2 ee[16];
    #pragma unroll
    for (int k = 0; k < 16; ++k) {
        int e = base + k * 256 + tid;
        eb[k] = -1;
        if (e < N_EDGES) {
            int s = src[e], d = dst[e];
            int b = d >> 9;
            eb[k] = b;
            unsigned short nh = __half_as_ushort(__float2half_rn(dinv[s] * dinv[d]));
            ee[k] = make_int2(s, ((d & 511) << 16) | (int)nh);
            atomicAdd(&hist[b], 1);
        }
    }
    __syncthreads();
    for (int i = tid; i < NB; i += 256) bstart[i] = atomicAdd(&bcur[i], hist[i]);
    __syncthreads();
    #pragma unroll
    for (int k = 0; k < 16; ++k) {
        if (eb[k] >= 0) {
            int r = atomicAdd(&curs[eb[k]], 1);
            bpack[bstart[eb[k]] + r] = ee[k];
        }
    }
}

// ---------------- pass B: bucket -> exact CSR (node-sorted), L2-contained scatter ----------------
__global__ __launch_bounds__(512) void k_sort_bins(const int* __restrict__ offsets,
                                                   const int2* __restrict__ bpack,
                                                   int2* __restrict__ pack) {
    __shared__ int cur[512];
    const int tid = threadIdx.x;
    const int node0 = blockIdx.x << 9;
    int n = node0 + tid;
    cur[tid] = (n < N_NODES) ? offsets[n] : 0;
    __syncthreads();
    const int s0 = offsets[node0];
    const int endn = (node0 + 512 < N_NODES) ? node0 + 512 : N_NODES;
    const int s1 = offsets[endn];
    for (int i = s0 + tid; i < s1; i += 512) {
        int2 p = bpack[i];
        int ld = p.y >> 16;
        int pos = atomicAdd(&cur[ld], 1);
        float w = __half2float(__ushort_as_half((unsigned short)(p.y & 0xffff)));
        pack[pos] = make_int2(p.x, __float_as_int(w));
    }
}

// ---------------- GEMM1 via MFMA: h = x @ W1, f16 out ----------------
__global__ __launch_bounds__(256) void k_gemm1(const float* __restrict__ x,
                                               const _Float16* __restrict__ Bfrag,
                                               __half* __restrict__ hh) {
    const int tid = threadIdx.x;
    const int wave = tid >> 6, lane = tid & 63;
    const int lrow = lane & 15;
    const int lk = lane >> 4;
    const int row = blockIdx.x * 64 + wave * 16 + lrow;
    const int rowc = (row < N_NODES) ? row : (N_NODES - 1);
    const float* xp = x + (size_t)rowc * 256 + lk * 8;
    const h8* bp = (const h8*)Bfrag + lane;

    f4 acc0 = {0.f, 0.f, 0.f, 0.f};
    f4 acc1 = {0.f, 0.f, 0.f, 0.f};
    f4 acc2 = {0.f, 0.f, 0.f, 0.f};
    f4 acc3 = {0.f, 0.f, 0.f, 0.f};

    #pragma unroll 2
    for (int ks = 0; ks < 8; ++ks) {
        float4 a01 = *(const float4*)(xp + ks * 32);
        float4 a23 = *(const float4*)(xp + ks * 32 + 4);
        h8 af;
        af[0] = (_Float16)a01.x; af[1] = (_Float16)a01.y;
        af[2] = (_Float16)a01.z; af[3] = (_Float16)a01.w;
        af[4] = (_Float16)a23.x; af[5] = (_Float16)a23.y;
        af[6] = (_Float16)a23.z; af[7] = (_Float16)a23.w;
        h8 b0 = bp[(ks * 4 + 0) * 64];
        h8 b1 = bp[(ks * 4 + 1) * 64];
        h8 b2 = bp[(ks * 4 + 2) * 64];
        h8 b3 = bp[(ks * 4 + 3) * 64];
        acc0 = __builtin_amdgcn_mfma_f32_16x16x32_f16(af, b0, acc0, 0, 0, 0);
        acc1 = __builtin_amdgcn_mfma_f32_16x16x32_f16(af, b1, acc1, 0, 0, 0);
        acc2 = __builtin_amdgcn_mfma_f32_16x16x32_f16(af, b2, acc2, 0, 0, 0);
        acc3 = __builtin_amdgcn_mfma_f32_16x16x32_f16(af, b3, acc3, 0, 0, 0);
    }

    const int orow0 = blockIdx.x * 64 + wave * 16 + lk * 4;
    const bool evlane = ((lane & 1) == 0);
#define STORE_TILE(ACC, NT) { \
    _Pragma("unroll") \
    for (int r = 0; r < 4; ++r) { \
        float v = ACC[r]; \
        float o = __shfl_xor(v, 1); \
        int orow = orow0 + r; \
        if (evlane && orow < N_NODES) \
            *(__half2*)&hh[(size_t)orow * 64 + (NT) * 16 + lrow] = __floats2half2_rn(v, o); \
    } }
    STORE_TILE(acc0, 0)
    STORE_TILE(acc1, 1)
    STORE_TILE(acc2, 2)
    STORE_TILE(acc3, 3)
#undef STORE_TILE
}

// ---------------- fused agg1 + self-loop + b1 + relu + GEMM2 (fp16 gather, register accum) ----------------
__global__ __launch_bounds__(256) void k_agg1_gemm2(const int* __restrict__ offsets,
                                                    const int2* __restrict__ pack,
                                                    const float* __restrict__ dinv,
                                                    const __half* __restrict__ hh,
                                                    const float* __restrict__ b1,
                                                    const float* __restrict__ W2,
                                                    __half* __restrict__ h2h) {
    __shared__ float W2s[64][17];
    __shared__ float h1s[4][64];
    const int tid = threadIdx.x;
    for (int i = tid; i < 64 * 16; i += 256) W2s[i >> 4][i & 15] = W2[i];
    __syncthreads();

    const int wave = tid >> 6;
    const int lane = tid & 63;
    const int node = blockIdx.x * 4 + wave;
    const int half_id = lane >> 5;
    const int l = lane & 31;          // channels 2l, 2l+1

    const int s0 = offsets[node], s1 = offsets[node + 1];
    float2 a0 = {0.f, 0.f}, a1 = {0.f, 0.f}, a2 = {0.f, 0.f}, a3 = {0.f, 0.f};
    int i = s0 + half_id;
    for (; i + 6 < s1; i += 8) {
        int2 p0 = pack[i], p1 = pack[i + 2], p2 = pack[i + 4], p3 = pack[i + 6];
        float2 f0 = __half22float2(*(const __half2*)(hh + (size_t)p0.x * 64 + 2 * l));
        float2 f1 = __half22float2(*(const __half2*)(hh + (size_t)p1.x * 64 + 2 * l));
        float2 f2 = __half22float2(*(const __half2*)(hh + (size_t)p2.x * 64 + 2 * l));
        float2 f3 = __half22float2(*(const __half2*)(hh + (size_t)p3.x * 64 + 2 * l));
        float w0 = __int_as_float(p0.y), w1 = __int_as_float(p1.y);
        float w2 = __int_as_float(p2.y), w3 = __int_as_float(p3.y);
        a0.x = fmaf(f0.x, w0, a0.x); a0.y = fmaf(f0.y, w0, a0.y);
        a1.x = fmaf(f1.x, w1, a1.x); a1.y = fmaf(f1.y, w1, a1.y);
        a2.x = fmaf(f2.x, w2, a2.x); a2.y = fmaf(f2.y, w2, a2.y);
        a3.x = fmaf(f3.x, w3, a3.x); a3.y = fmaf(f3.y, w3, a3.y);
    }
    for (; i < s1; i += 2) {
        int2 p = pack[i];
        float w = __int_as_float(p.y);
        float2 f = __half22float2(*(const __half2*)(hh + (size_t)p.x * 64 + 2 * l));
        a0.x = fmaf(f.x, w, a0.x); a0.y = fmaf(f.y, w, a0.y);
    }
    float2 acc;
    acc.x = (a0.x + a1.x) + (a2.x + a3.x);
    acc.y = (a0.y + a1.y) + (a2.y + a3.y);
    acc.x += __shfl_xor(acc.x, 32);
    acc.y += __shfl_xor(acc.y, 32);
    if (half_id == 0) {
        const float di = dinv[node];
        const float dii = di * di;
        float2 sf = __half22float2(*(const __half2*)(hh + (size_t)node * 64 + 2 * l));
        acc.x = fmaf(sf.x, dii, acc.x) + b1[2 * l];
        acc.y = fmaf(sf.y, dii, acc.y) + b1[2 * l + 1];
        h1s[wave][2 * l]     = fmaxf(acc.x, 0.f);
        h1s[wave][2 * l + 1] = fmaxf(acc.y, 0.f);
    }
    // same-wave LDS write->read (lgkmcnt-ordered)
    const int j = lane >> 4, cc = lane & 15;
    float g = 0.f;
    #pragma unroll
    for (int t = 0; t < 16; ++t) {
        int k = j * 16 + t;
        g = fmaf(h1s[wave][k], W2s[k][cc], g);
    }
    g += __shfl_xor(g, 16);
    g += __shfl_xor(g, 32);
    float go = __shfl_xor(g, 1);
    if (lane < 16 && (cc & 1) == 0) {
        *(__half2*)&h2h[(size_t)node * 16 + cc] = __floats2half2_rn(g, go);
    }
}

// ---------------- fused agg2 + self-loop + b2 + log_softmax (fp16 gather) ----------------
__global__ __launch_bounds__(256) void k_agg2_final(const int* __restrict__ offsets,
                                                    const int2* __restrict__ pack,
                                                    const float* __restrict__ dinv,
                                                    const __half* __restrict__ h2h,
                                                    const float* __restrict__ b2,
                                                    float* __restrict__ out) {
    const int tid = threadIdx.x;
    const int wave = tid >> 6;
    const int lane = tid & 63;
    const int node = blockIdx.x * 4 + wave;
    const int j = lane >> 3, cp = lane & 7;   // channels 2cp, 2cp+1

    const int s0 = offsets[node], s1 = offsets[node + 1];
    float2 a0 = {0.f, 0.f}, a1 = {0.f, 0.f};
    int i = s0 + j;
    for (; i + 8 < s1; i += 16) {
        int2 p0 = pack[i], p1 = pack[i + 8];
        float2 f0 = __half22float2(*(const __half2*)(h2h + (size_t)p0.x * 16 + 2 * cp));
        float2 f1 = __half22float2(*(const __half2*)(h2h + (size_t)p1.x * 16 + 2 * cp));
        float w0 = __int_as_float(p0.y), w1 = __int_as_float(p1.y);
        a0.x = fmaf(f0.x, w0, a0.x); a0.y = fmaf(f0.y, w0, a0.y);
        a1.x = fmaf(f1.x, w1, a1.x); a1.y = fmaf(f1.y, w1, a1.y);
    }
    for (; i < s1; i += 8) {
        int2 p = pack[i];
        float w = __int_as_float(p.y);
        float2 f = __half22float2(*(const __half2*)(h2h + (size_t)p.x * 16 + 2 * cp));
        a0.x = fmaf(f.x, w, a0.x); a0.y = fmaf(f.y, w, a0.y);
    }
    float2 z;
    z.x = a0.x + a1.x;
    z.y = a0.y + a1.y;
    z.x += __shfl_xor(z.x, 8);  z.y += __shfl_xor(z.y, 8);
    z.x += __shfl_xor(z.x, 16); z.y += __shfl_xor(z.y, 16);
    z.x += __shfl_xor(z.x, 32); z.y += __shfl_xor(z.y, 32);

    const float di = dinv[node];
    const float dii = di * di;
    float2 sf = __half22float2(*(const __half2*)(h2h + (size_t)node * 16 + 2 * cp));
    z.x = fmaf(sf.x, dii, z.x) + b2[2 * cp];
    z.y = fmaf(sf.y, dii, z.y) + b2[2 * cp + 1];

    float m = fmaxf(z.x, z.y);
    m = fmaxf(m, __shfl_xor(m, 1, 8));
    m = fmaxf(m, __shfl_xor(m, 2, 8));
    m = fmaxf(m, __shfl_xor(m, 4, 8));
    float ex = __expf(z.x - m), ey = __expf(z.y - m);
    float s = ex + ey;
    s += __shfl_xor(s, 1, 8);
    s += __shfl_xor(s, 2, 8);
    s += __shfl_xor(s, 4, 8);
    float ls = logf(s);
    if (j == 0) {
        float2 o;
        o.x = z.x - m - ls;
        o.y = z.y - m - ls;
        *(float2*)&out[(size_t)node * 16 + 2 * cp] = o;
    }
}

extern "C" void kernel_launch(void* const* d_in, const int* in_sizes, int n_in,
                              void* d_out, int out_size, void* d_ws, size_t ws_size,
                              hipStream_t stream) {
    const float* x  = (const float*)d_in[0];
    const int* ei   = (const int*)d_in[1];
    const float* W1 = (const float*)d_in[2];
    const float* b1 = (const float*)d_in[3];
    const float* W2 = (const float*)d_in[4];
    const float* b2 = (const float*)d_in[5];
    const int* src = ei;
    const int* dst = ei + N_EDGES;

    // workspace layout (int units): ints before bpack = 8192+100000+100000+100001+391+196+1? ->
    // Bfrag 8192 | degi 100000 | dinv 100000 | offsets 100001 | bsums 391 | bcur 196 | pad ->
    // 8192+100000+100000+100001+391+196 = 308780 (even) -> bpack 8B aligned
    _Float16* Bfrag = (_Float16*)d_ws;                   // 16384 halves = 8192 ints
    int*    degi    = (int*)d_ws + 8192;                 // N
    float*  dinv    = (float*)(degi + N_NODES);          // N
    int*    offsets = (int*)(dinv + N_NODES);            // N+1
    int*    bsums   = offsets + N_NODES + 1;             // 391
    int*    bcur    = bsums + NBLK_NODES;                // 196
    int2*   bpack   = (int2*)(bcur + NB);                // E int2
    int2*   pack    = bpack + N_EDGES;                   // E int2
    __half* hh      = (__half*)(pack + N_EDGES);         // N*64 half
    __half* h2h     = hh + (size_t)N_NODES * 64;         // N*16 half
    float*  out     = (float*)d_out;

    hipMemsetAsync(degi, 0, N_NODES * sizeof(int), stream);

    k_count_deg<<<(N_EDGES + 255) / 256, 256, 0, stream>>>(dst, degi);
    k_dinv<<<NBLK_NODES, 256, 0, stream>>>(degi, dinv);
    k_prepW1<<<64, 256, 0, stream>>>(W1, Bfrag);
    k_block_sum<<<NBLK_NODES, 256, 0, stream>>>(degi, bsums);
    k_scan_bsums<<<1, 512, 0, stream>>>(bsums, NBLK_NODES);
    k_scan_block<<<NBLK_NODES, 256, 0, stream>>>(degi, bsums, offsets);
    k_init_bcur<<<1, 256, 0, stream>>>(offsets, bcur);
    k_fill_bins<<<(N_EDGES + 4095) / 4096, 256, 0, stream>>>(src, dst, dinv, bcur, bpack);
    k_sort_bins<<<NB, 512, 0, stream>>>(offsets, bpack, pack);
    k_gemm1<<<(N_NODES + 63) / 64, 256, 0, stream>>>(x, Bfrag, hh);
    k_agg1_gemm2<<<N_NODES / 4, 256, 0, stream>>>(offsets, pack, dinv, hh, b1, W2, h2h);
    k_agg2_final<<<N_NODES / 4, 256, 0, stream>>>(offsets, pack, dinv, h2h, b2, out);
}

// Round 7
// 207.558 us; speedup vs baseline: 6.5050x; 1.2869x over previous
//
#include <hip/hip_runtime.h>
#include <hip/hip_fp16.h>
#include <math.h>

#define N_NODES 100000
#define N_EDGES 1600000
#define FIN 256
#define NB 196           // ceil(100000/512): 512-node dst buckets

typedef _Float16 h8 __attribute__((ext_vector_type(8)));
typedef float f4 __attribute__((ext_vector_type(4)));

// ---------------- bucket histogram over dst (LDS-staged) ----------------
__global__ __launch_bounds__(256) void k_hist196(const int* __restrict__ dst, int* __restrict__ bcnt) {
    __shared__ int hist[NB];
    const int tid = threadIdx.x;
    if (tid < NB) hist[tid] = 0;
    __syncthreads();
    const int base = blockIdx.x * 2048;
    #pragma unroll
    for (int k = 0; k < 8; ++k) {
        int e = base + k * 256 + tid;
        if (e < N_EDGES) atomicAdd(&hist[dst[e] >> 9], 1);
    }
    __syncthreads();
    if (tid < NB && hist[tid] > 0) atomicAdd(&bcnt[tid], hist[tid]);
}

// ---------------- exclusive scan of 196 bucket counts -> bcur (pass A cursors) + bbase ----------------
__global__ __launch_bounds__(256) void k_scan196(const int* __restrict__ bcnt,
                                                 int* __restrict__ bcur, int* __restrict__ bbase) {
    __shared__ int sd[256];
    int t = threadIdx.x;
    int v = (t < NB) ? bcnt[t] : 0;
    sd[t] = v;
    __syncthreads();
    for (int off = 1; off < 256; off <<= 1) {
        int tv = (t >= off) ? sd[t - off] : 0;
        __syncthreads();
        sd[t] += tv;
        __syncthreads();
    }
    if (t < NB) { bcur[t] = sd[t] - v; bbase[t] = sd[t] - v; }
    if (t == NB - 1) bbase[NB] = sd[t];
}

// ---------------- W1 -> f16 MFMA B-fragment layout ----------------
__global__ __launch_bounds__(256) void k_prepW1(const float* __restrict__ W1, _Float16* __restrict__ Bfrag) {
    int i = blockIdx.x * 256 + threadIdx.x;   // 0..16383
    int j = i & 7, lane = (i >> 3) & 63, nt = (i >> 9) & 3, ks = i >> 11;
    int k = ks * 32 + ((lane >> 4) << 3) + j;
    int c = nt * 16 + (lane & 15);
    Bfrag[i] = (_Float16)W1[k * 64 + c];
}

// ---------------- pass A: bin edges into 512-node buckets, payload = (local_dst<<17)|src ----------------
__global__ __launch_bounds__(256) void k_fill_bins(const int* __restrict__ src, const int* __restrict__ dst,
                                                   int* __restrict__ bcur, int* __restrict__ bpack) {
    __shared__ int hist[NB], curs[NB], bstart[NB];
    const int tid = threadIdx.x;
    for (int i = tid; i < NB; i += 256) { hist[i] = 0; curs[i] = 0; }
    __syncthreads();
    const int base = blockIdx.x * 4096;
    int eb[16], ee[16];
    #pragma unroll
    for (int k = 0; k < 16; ++k) {
        int e = base + k * 256 + tid;
        eb[k] = -1;
        if (e < N_EDGES) {
            int s = src[e], d = dst[e];
            int b = d >> 9;
            eb[k] = b;
            ee[k] = ((d & 511) << 17) | s;
            atomicAdd(&hist[b], 1);
        }
    }
    __syncthreads();
    for (int i = tid; i < NB; i += 256) if (hist[i] > 0) bstart[i] = atomicAdd(&bcur[i], hist[i]);
    __syncthreads();
    #pragma unroll
    for (int k = 0; k < 16; ++k) {
        if (eb[k] >= 0) {
            int r = atomicAdd(&curs[eb[k]], 1);
            bpack[bstart[eb[k]] + r] = ee[k];
        }
    }
}

// ---------------- pass B: per bucket -> node histogram, scan, dinv, offsets, sorted src ----------------
__global__ __launch_bounds__(512) void k_sort_bins(const int* __restrict__ bbase,
                                                   const int* __restrict__ bpack,
                                                   int* __restrict__ pack,
                                                   int* __restrict__ offsets,
                                                   float* __restrict__ dinv) {
    __shared__ int hist[512], sd[512], cur[512];
    const int tid = threadIdx.x;
    const int b = blockIdx.x;
    const int node0 = b << 9;
    hist[tid] = 0;
    __syncthreads();
    const int s0 = bbase[b], s1 = bbase[b + 1];
    for (int i = s0 + tid; i < s1; i += 512) atomicAdd(&hist[bpack[i] >> 17], 1);
    __syncthreads();
    const int deg = hist[tid];
    sd[tid] = deg;
    __syncthreads();
    for (int off = 1; off < 512; off <<= 1) {
        int tv = (tid >= off) ? sd[tid - off] : 0;
        __syncthreads();
        sd[tid] += tv;
        __syncthreads();
    }
    const int excl = sd[tid] - deg;
    const int n = node0 + tid;
    cur[tid] = s0 + excl;
    if (n < N_NODES) {
        offsets[n] = s0 + excl;
        dinv[n] = rsqrtf((float)deg + 1.0f);
    }
    if (b == NB - 1 && tid == 0) offsets[N_NODES] = N_EDGES;
    __syncthreads();
    for (int i = s0 + tid; i < s1; i += 512) {
        int v = bpack[i];
        int pos = atomicAdd(&cur[v >> 17], 1);
        pack[pos] = v & 0x1FFFF;
    }
}

// ---------------- GEMM1 via MFMA: h' = dinv * (x @ W1), f16 out ----------------
__global__ __launch_bounds__(256) void k_gemm1(const float* __restrict__ x,
                                               const _Float16* __restrict__ Bfrag,
                                               const float* __restrict__ dinv,
                                               __half* __restrict__ hh) {
    const int tid = threadIdx.x;
    const int wave = tid >> 6, lane = tid & 63;
    const int lrow = lane & 15;
    const int lk = lane >> 4;
    const int row = blockIdx.x * 64 + wave * 16 + lrow;
    const int rowc = (row < N_NODES) ? row : (N_NODES - 1);
    const float di = dinv[rowc];
    const float* xp = x + (size_t)rowc * 256 + lk * 8;
    const h8* bp = (const h8*)Bfrag + lane;

    f4 acc0 = {0.f, 0.f, 0.f, 0.f};
    f4 acc1 = {0.f, 0.f, 0.f, 0.f};
    f4 acc2 = {0.f, 0.f, 0.f, 0.f};
    f4 acc3 = {0.f, 0.f, 0.f, 0.f};

    #pragma unroll 2
    for (int ks = 0; ks < 8; ++ks) {
        float4 a01 = *(const float4*)(xp + ks * 32);
        float4 a23 = *(const float4*)(xp + ks * 32 + 4);
        h8 af;
        af[0] = (_Float16)(a01.x * di); af[1] = (_Float16)(a01.y * di);
        af[2] = (_Float16)(a01.z * di); af[3] = (_Float16)(a01.w * di);
        af[4] = (_Float16)(a23.x * di); af[5] = (_Float16)(a23.y * di);
        af[6] = (_Float16)(a23.z * di); af[7] = (_Float16)(a23.w * di);
        h8 b0 = bp[(ks * 4 + 0) * 64];
        h8 b1 = bp[(ks * 4 + 1) * 64];
        h8 b2 = bp[(ks * 4 + 2) * 64];
        h8 b3 = bp[(ks * 4 + 3) * 64];
        acc0 = __builtin_amdgcn_mfma_f32_16x16x32_f16(af, b0, acc0, 0, 0, 0);
        acc1 = __builtin_amdgcn_mfma_f32_16x16x32_f16(af, b1, acc1, 0, 0, 0);
        acc2 = __builtin_amdgcn_mfma_f32_16x16x32_f16(af, b2, acc2, 0, 0, 0);
        acc3 = __builtin_amdgcn_mfma_f32_16x16x32_f16(af, b3, acc3, 0, 0, 0);
    }

    const int orow0 = blockIdx.x * 64 + wave * 16 + lk * 4;
    const bool evlane = ((lane & 1) == 0);
#define STORE_TILE(ACC, NT) { \
    _Pragma("unroll") \
    for (int r = 0; r < 4; ++r) { \
        float v = ACC[r]; \
        float o = __shfl_xor(v, 1); \
        int orow = orow0 + r; \
        if (evlane && orow < N_NODES) \
            *(__half2*)&hh[(size_t)orow * 64 + (NT) * 16 + lrow] = __floats2half2_rn(v, o); \
    } }
    STORE_TILE(acc0, 0)
    STORE_TILE(acc1, 1)
    STORE_TILE(acc2, 2)
    STORE_TILE(acc3, 3)
#undef STORE_TILE
}

// ---------------- fused agg1 + self-loop + b1 + relu + GEMM2, h2' = dinv*h2 out ----------------
// wave per node; half-wave (32 lanes x half2) per edge, unroll-4 -> 8 gathers in flight
__global__ __launch_bounds__(256) void k_agg1_gemm2(const int* __restrict__ offsets,
                                                    const int* __restrict__ pack,
                                                    const float* __restrict__ dinv,
                                                    const __half* __restrict__ hh,
                                                    const float* __restrict__ b1,
                                                    const float* __restrict__ W2,
                                                    __half* __restrict__ h2h) {
    __shared__ float W2s[64][17];
    __shared__ float h1s[4][64];
    const int tid = threadIdx.x;
    for (int i = tid; i < 64 * 16; i += 256) W2s[i >> 4][i & 15] = W2[i];
    __syncthreads();

    const int wave = tid >> 6;
    const int lane = tid & 63;
    const int node = blockIdx.x * 4 + wave;
    const int half_id = lane >> 5;
    const int l = lane & 31;          // channels 2l, 2l+1

    const int s0 = offsets[node], s1 = offsets[node + 1];
    float2 a0 = {0.f, 0.f}, a1 = {0.f, 0.f}, a2 = {0.f, 0.f}, a3 = {0.f, 0.f};
    int i = s0 + half_id;
    for (; i + 6 < s1; i += 8) {
        int p0 = pack[i], p1 = pack[i + 2], p2 = pack[i + 4], p3 = pack[i + 6];
        float2 f0 = __half22float2(*(const __half2*)(hh + (size_t)p0 * 64 + 2 * l));
        float2 f1 = __half22float2(*(const __half2*)(hh + (size_t)p1 * 64 + 2 * l));
        float2 f2 = __half22float2(*(const __half2*)(hh + (size_t)p2 * 64 + 2 * l));
        float2 f3 = __half22float2(*(const __half2*)(hh + (size_t)p3 * 64 + 2 * l));
        a0.x += f0.x; a0.y += f0.y;
        a1.x += f1.x; a1.y += f1.y;
        a2.x += f2.x; a2.y += f2.y;
        a3.x += f3.x; a3.y += f3.y;
    }
    for (; i < s1; i += 2) {
        int p = pack[i];
        float2 f = __half22float2(*(const __half2*)(hh + (size_t)p * 64 + 2 * l));
        a0.x += f.x; a0.y += f.y;
    }
    float2 acc;
    acc.x = (a0.x + a1.x) + (a2.x + a3.x);
    acc.y = (a0.y + a1.y) + (a2.y + a3.y);
    acc.x += __shfl_xor(acc.x, 32);
    acc.y += __shfl_xor(acc.y, 32);
    const float di = dinv[node];
    if (half_id == 0) {
        float2 sf = __half22float2(*(const __half2*)(hh + (size_t)node * 64 + 2 * l));
        acc.x = (acc.x + sf.x) * di + b1[2 * l];
        acc.y = (acc.y + sf.y) * di + b1[2 * l + 1];
        h1s[wave][2 * l]     = fmaxf(acc.x, 0.f);
        h1s[wave][2 * l + 1] = fmaxf(acc.y, 0.f);
    }
    // same-wave LDS write->read (lgkmcnt-ordered)
    const int j = lane >> 4, cc = lane & 15;
    float g = 0.f;
    #pragma unroll
    for (int t = 0; t < 16; ++t) {
        int k = j * 16 + t;
        g = fmaf(h1s[wave][k], W2s[k][cc], g);
    }
    g += __shfl_xor(g, 16);
    g += __shfl_xor(g, 32);
    g *= di;                           // h2' = dinv * h2
    float go = __shfl_xor(g, 1);
    if (lane < 16 && (cc & 1) == 0) {
        *(__half2*)&h2h[(size_t)node * 16 + cc] = __floats2half2_rn(g, go);
    }
}

// ---------------- fused agg2 + self-loop + b2 + log_softmax ----------------
__global__ __launch_bounds__(256) void k_agg2_final(const int* __restrict__ offsets,
                                                    const int* __restrict__ pack,
                                                    const float* __restrict__ dinv,
                                                    const __half* __restrict__ h2h,
                                                    const float* __restrict__ b2,
                                                    float* __restrict__ out) {
    const int tid = threadIdx.x;
    const int wave = tid >> 6;
    const int lane = tid & 63;
    const int node = blockIdx.x * 4 + wave;
    const int j = lane >> 3, cp = lane & 7;   // channels 2cp, 2cp+1

    const int s0 = offsets[node], s1 = offsets[node + 1];
    float2 a0 = {0.f, 0.f}, a1 = {0.f, 0.f};
    int i = s0 + j;
    for (; i + 8 < s1; i += 16) {
        int p0 = pack[i], p1 = pack[i + 8];
        float2 f0 = __half22float2(*(const __half2*)(h2h + (size_t)p0 * 16 + 2 * cp));
        float2 f1 = __half22float2(*(const __half2*)(h2h + (size_t)p1 * 16 + 2 * cp));
        a0.x += f0.x; a0.y += f0.y;
        a1.x += f1.x; a1.y += f1.y;
    }
    for (; i < s1; i += 8) {
        int p = pack[i];
        float2 f = __half22float2(*(const __half2*)(h2h + (size_t)p * 16 + 2 * cp));
        a0.x += f.x; a0.y += f.y;
    }
    float2 z;
    z.x = a0.x + a1.x;
    z.y = a0.y + a1.y;
    z.x += __shfl_xor(z.x, 8);  z.y += __shfl_xor(z.y, 8);
    z.x += __shfl_xor(z.x, 16); z.y += __shfl_xor(z.y, 16);
    z.x += __shfl_xor(z.x, 32); z.y += __shfl_xor(z.y, 32);

    const float di = dinv[node];
    float2 sf = __half22float2(*(const __half2*)(h2h + (size_t)node * 16 + 2 * cp));
    z.x = (z.x + sf.x) * di + b2[2 * cp];
    z.y = (z.y + sf.y) * di + b2[2 * cp + 1];

    float m = fmaxf(z.x, z.y);
    m = fmaxf(m, __shfl_xor(m, 1, 8));
    m = fmaxf(m, __shfl_xor(m, 2, 8));
    m = fmaxf(m, __shfl_xor(m, 4, 8));
    float ex = __expf(z.x - m), ey = __expf(z.y - m);
    float s = ex + ey;
    s += __shfl_xor(s, 1, 8);
    s += __shfl_xor(s, 2, 8);
    s += __shfl_xor(s, 4, 8);
    float ls = logf(s);
    if (j == 0) {
        float2 o;
        o.x = z.x - m - ls;
        o.y = z.y - m - ls;
        *(float2*)&out[(size_t)node * 16 + 2 * cp] = o;
    }
}

extern "C" void kernel_launch(void* const* d_in, const int* in_sizes, int n_in,
                              void* d_out, int out_size, void* d_ws, size_t ws_size,
                              hipStream_t stream) {
    const float* x  = (const float*)d_in[0];
    const int* ei   = (const int*)d_in[1];
    const float* W1 = (const float*)d_in[2];
    const float* b1 = (const float*)d_in[3];
    const float* W2 = (const float*)d_in[4];
    const float* b2 = (const float*)d_in[5];
    const int* src = ei;
    const int* dst = ei + N_EDGES;

    // workspace layout (int units)
    _Float16* Bfrag = (_Float16*)d_ws;                   // 16384 halves = 8192 ints
    int*    bcnt    = (int*)d_ws + 8192;                 // NB
    int*    bcur    = bcnt + NB;                         // NB
    int*    bbase   = bcur + NB;                         // NB+1
    int*    offsets = bbase + NB + 1;                    // N+1
    float*  dinv    = (float*)(offsets + N_NODES + 1);   // N
    int*    bpack   = (int*)(dinv + N_NODES);            // E
    int*    pack    = bpack + N_EDGES;                   // E
    __half* hh      = (__half*)(pack + N_EDGES);         // N*64 half
    __half* h2h     = hh + (size_t)N_NODES * 64;         // N*16 half
    float*  out     = (float*)d_out;

    hipMemsetAsync(bcnt, 0, NB * sizeof(int), stream);

    k_hist196<<<(N_EDGES + 2047) / 2048, 256, 0, stream>>>(dst, bcnt);
    k_scan196<<<1, 256, 0, stream>>>(bcnt, bcur, bbase);
    k_prepW1<<<64, 256, 0, stream>>>(W1, Bfrag);
    k_fill_bins<<<(N_EDGES + 4095) / 4096, 256, 0, stream>>>(src, dst, bcur, bpack);
    k_sort_bins<<<NB, 512, 0, stream>>>(bbase, bpack, pack, offsets, dinv);
    k_gemm1<<<(N_NODES + 63) / 64, 256, 0, stream>>>(x, Bfrag, dinv, hh);
    k_agg1_gemm2<<<N_NODES / 4, 256, 0, stream>>>(offsets, pack, dinv, hh, b1, W2, h2h);
    k_agg2_final<<<N_NODES / 4, 256, 0, stream>>>(offsets, pack, dinv, h2h, b2, out);
}

// Round 8
// 181.700 us; speedup vs baseline: 7.4307x; 1.1423x over previous
//
#include <hip/hip_runtime.h>
#include <hip/hip_fp16.h>
#include <math.h>

#define N_NODES 100000
#define N_EDGES 1600000
#define FIN 256
#define NB 196           // ceil(100000/512): 512-node dst buckets
#define CAP 10240        // bucket capacity: mean 8163, sigma ~90 -> +22 sigma

typedef _Float16 h8 __attribute__((ext_vector_type(8)));
typedef float f4 __attribute__((ext_vector_type(4)));

// ---------------- W1 -> f16 MFMA B-fragment layout ----------------
__global__ __launch_bounds__(256) void k_prepW1(const float* __restrict__ W1, _Float16* __restrict__ Bfrag) {
    int i = blockIdx.x * 256 + threadIdx.x;   // 0..16383
    int j = i & 7, lane = (i >> 3) & 63, nt = (i >> 9) & 3, ks = i >> 11;
    int k = ks * 32 + ((lane >> 4) << 3) + j;
    int c = nt * 16 + (lane & 15);
    Bfrag[i] = (_Float16)W1[k * 64 + c];
}

// ---------------- pass A: bin edges into fixed-capacity 512-node buckets ----------------
// payload = (local_dst<<17)|src ; bucket b region = [b*CAP, b*CAP+cnt)
__global__ __launch_bounds__(256) void k_fill_bins(const int* __restrict__ src, const int* __restrict__ dst,
                                                   int* __restrict__ bcur, int* __restrict__ bpack) {
    __shared__ int hist[NB], curs[NB], bstart[NB];
    const int tid = threadIdx.x;
    for (int i = tid; i < NB; i += 256) { hist[i] = 0; curs[i] = 0; }
    __syncthreads();
    const int base = blockIdx.x * 4096;
    int eb[16], ee[16];
    #pragma unroll
    for (int k = 0; k < 16; ++k) {
        int e = base + k * 256 + tid;
        eb[k] = -1;
        if (e < N_EDGES) {
            int s = src[e], d = dst[e];
            int b = d >> 9;
            eb[k] = b;
            ee[k] = ((d & 511) << 17) | s;
            atomicAdd(&hist[b], 1);
        }
    }
    __syncthreads();
    for (int i = tid; i < NB; i += 256)
        if (hist[i] > 0) bstart[i] = i * CAP + atomicAdd(&bcur[i], hist[i]);
    __syncthreads();
    #pragma unroll
    for (int k = 0; k < 16; ++k) {
        if (eb[k] >= 0) {
            int r = atomicAdd(&curs[eb[k]], 1);
            bpack[bstart[eb[k]] + r] = ee[k];
        }
    }
}

// ---------------- pass B: per bucket -> node histogram, scan, dinv, starts/ends, sorted src ----------------
__global__ __launch_bounds__(512) void k_sort_bins(const int* __restrict__ bcur,
                                                   const int* __restrict__ bpack,
                                                   int* __restrict__ pack,
                                                   int* __restrict__ starts,
                                                   int* __restrict__ ends,
                                                   float* __restrict__ dinv) {
    __shared__ int hist[512], sd[512], cur[512];
    const int tid = threadIdx.x;
    const int b = blockIdx.x;
    const int node0 = b << 9;
    hist[tid] = 0;
    __syncthreads();
    const int s0 = b * CAP, s1 = s0 + bcur[b];
    for (int i = s0 + tid; i < s1; i += 512) atomicAdd(&hist[bpack[i] >> 17], 1);
    __syncthreads();
    const int deg = hist[tid];
    sd[tid] = deg;
    __syncthreads();
    for (int off = 1; off < 512; off <<= 1) {
        int tv = (tid >= off) ? sd[tid - off] : 0;
        __syncthreads();
        sd[tid] += tv;
        __syncthreads();
    }
    const int excl = sd[tid] - deg;
    const int n = node0 + tid;
    cur[tid] = s0 + excl;
    if (n < N_NODES) {
        starts[n] = s0 + excl;
        ends[n]   = s0 + excl + deg;
        dinv[n] = rsqrtf((float)deg + 1.0f);
    }
    __syncthreads();
    for (int i = s0 + tid; i < s1; i += 512) {
        int v = bpack[i];
        int pos = atomicAdd(&cur[v >> 17], 1);
        pack[pos] = v & 0x1FFFF;
    }
}

// ---------------- GEMM1 via MFMA: h' = dinv * (x @ W1), f16 out ----------------
__global__ __launch_bounds__(256) void k_gemm1(const float* __restrict__ x,
                                               const _Float16* __restrict__ Bfrag,
                                               const float* __restrict__ dinv,
                                               __half* __restrict__ hh) {
    const int tid = threadIdx.x;
    const int wave = tid >> 6, lane = tid & 63;
    const int lrow = lane & 15;
    const int lk = lane >> 4;
    const int row = blockIdx.x * 64 + wave * 16 + lrow;
    const int rowc = (row < N_NODES) ? row : (N_NODES - 1);
    const float di = dinv[rowc];
    const float* xp = x + (size_t)rowc * 256 + lk * 8;
    const h8* bp = (const h8*)Bfrag + lane;

    f4 acc0 = {0.f, 0.f, 0.f, 0.f};
    f4 acc1 = {0.f, 0.f, 0.f, 0.f};
    f4 acc2 = {0.f, 0.f, 0.f, 0.f};
    f4 acc3 = {0.f, 0.f, 0.f, 0.f};

    #pragma unroll 2
    for (int ks = 0; ks < 8; ++ks) {
        float4 a01 = *(const float4*)(xp + ks * 32);
        float4 a23 = *(const float4*)(xp + ks * 32 + 4);
        h8 af;
        af[0] = (_Float16)(a01.x * di); af[1] = (_Float16)(a01.y * di);
        af[2] = (_Float16)(a01.z * di); af[3] = (_Float16)(a01.w * di);
        af[4] = (_Float16)(a23.x * di); af[5] = (_Float16)(a23.y * di);
        af[6] = (_Float16)(a23.z * di); af[7] = (_Float16)(a23.w * di);
        h8 b0 = bp[(ks * 4 + 0) * 64];
        h8 b1 = bp[(ks * 4 + 1) * 64];
        h8 b2 = bp[(ks * 4 + 2) * 64];
        h8 b3 = bp[(ks * 4 + 3) * 64];
        acc0 = __builtin_amdgcn_mfma_f32_16x16x32_f16(af, b0, acc0, 0, 0, 0);
        acc1 = __builtin_amdgcn_mfma_f32_16x16x32_f16(af, b1, acc1, 0, 0, 0);
        acc2 = __builtin_amdgcn_mfma_f32_16x16x32_f16(af, b2, acc2, 0, 0, 0);
        acc3 = __builtin_amdgcn_mfma_f32_16x16x32_f16(af, b3, acc3, 0, 0, 0);
    }

    const int orow0 = blockIdx.x * 64 + wave * 16 + lk * 4;
    const bool evlane = ((lane & 1) == 0);
#define STORE_TILE(ACC, NT) { \
    _Pragma("unroll") \
    for (int r = 0; r < 4; ++r) { \
        float v = ACC[r]; \
        float o = __shfl_xor(v, 1); \
        int orow = orow0 + r; \
        if (evlane && orow < N_NODES) \
            *(__half2*)&hh[(size_t)orow * 64 + (NT) * 16 + lrow] = __floats2half2_rn(v, o); \
    } }
    STORE_TILE(acc0, 0)
    STORE_TILE(acc1, 1)
    STORE_TILE(acc2, 2)
    STORE_TILE(acc3, 3)
#undef STORE_TILE
}

// ---------------- fused agg1 + self-loop + b1 + relu + GEMM2, h2' = dinv*h2 out ----------------
// wave per node; 4 edge-slots x 16 lanes x 8B gathers, unroll 2 -> 8 edges in flight
__global__ __launch_bounds__(256) void k_agg1_gemm2(const int* __restrict__ starts,
                                                    const int* __restrict__ ends,
                                                    const int* __restrict__ pack,
                                                    const float* __restrict__ dinv,
                                                    const __half* __restrict__ hh,
                                                    const float* __restrict__ b1,
                                                    const float* __restrict__ W2,
                                                    __half* __restrict__ h2h) {
    __shared__ float W2s[64][17];
    __shared__ float h1s[4][64];
    const int tid = threadIdx.x;
    for (int i = tid; i < 64 * 16; i += 256) W2s[i >> 4][i & 15] = W2[i];
    __syncthreads();

    const int wave = tid >> 6;
    const int lane = tid & 63;
    const int node = blockIdx.x * 4 + wave;
    const int e4 = lane >> 4;        // edge slot 0..3
    const int l4 = lane & 15;        // channels 4*l4 .. 4*l4+3

    const int s0 = starts[node], s1 = ends[node];
    float4 A = {0.f, 0.f, 0.f, 0.f}, B = {0.f, 0.f, 0.f, 0.f};
    int i = s0;
    for (; i + 7 < s1; i += 8) {
        int p0 = pack[i + e4], p1 = pack[i + 4 + e4];
        uint2 r0 = *(const uint2*)(hh + (size_t)p0 * 64 + 4 * l4);
        uint2 r1 = *(const uint2*)(hh + (size_t)p1 * 64 + 4 * l4);
        float2 f00 = __half22float2(*(const __half2*)&r0.x);
        float2 f01 = __half22float2(*(const __half2*)&r0.y);
        float2 f10 = __half22float2(*(const __half2*)&r1.x);
        float2 f11 = __half22float2(*(const __half2*)&r1.y);
        A.x += f00.x; A.y += f00.y; A.z += f01.x; A.w += f01.y;
        B.x += f10.x; B.y += f10.y; B.z += f11.x; B.w += f11.y;
    }
    for (; i + 3 < s1; i += 4) {
        int p = pack[i + e4];
        uint2 r = *(const uint2*)(hh + (size_t)p * 64 + 4 * l4);
        float2 f0 = __half22float2(*(const __half2*)&r.x);
        float2 f1 = __half22float2(*(const __half2*)&r.y);
        A.x += f0.x; A.y += f0.y; A.z += f1.x; A.w += f1.y;
    }
    if (i + e4 < s1) {
        int p = pack[i + e4];
        uint2 r = *(const uint2*)(hh + (size_t)p * 64 + 4 * l4);
        float2 f0 = __half22float2(*(const __half2*)&r.x);
        float2 f1 = __half22float2(*(const __half2*)&r.y);
        A.x += f0.x; A.y += f0.y; A.z += f1.x; A.w += f1.y;
    }
    A.x += B.x; A.y += B.y; A.z += B.z; A.w += B.w;
    // reduce across the 4 edge slots (lanes 16 apart)
    A.x += __shfl_xor(A.x, 16); A.y += __shfl_xor(A.y, 16);
    A.z += __shfl_xor(A.z, 16); A.w += __shfl_xor(A.w, 16);
    A.x += __shfl_xor(A.x, 32); A.y += __shfl_xor(A.y, 32);
    A.z += __shfl_xor(A.z, 32); A.w += __shfl_xor(A.w, 32);

    const float di = dinv[node];
    if (lane < 16) {
        uint2 sr = *(const uint2*)(hh + (size_t)node * 64 + 4 * l4);
        float2 sf0 = __half22float2(*(const __half2*)&sr.x);
        float2 sf1 = __half22float2(*(const __half2*)&sr.y);
        h1s[wave][4 * l4 + 0] = fmaxf((A.x + sf0.x) * di + b1[4 * l4 + 0], 0.f);
        h1s[wave][4 * l4 + 1] = fmaxf((A.y + sf0.y) * di + b1[4 * l4 + 1], 0.f);
        h1s[wave][4 * l4 + 2] = fmaxf((A.z + sf1.x) * di + b1[4 * l4 + 2], 0.f);
        h1s[wave][4 * l4 + 3] = fmaxf((A.w + sf1.y) * di + b1[4 * l4 + 3], 0.f);
    }
    // same-wave LDS write->read (lgkmcnt-ordered)
    const int j = lane >> 4, cc = lane & 15;
    float g = 0.f;
    #pragma unroll
    for (int t = 0; t < 16; ++t) {
        int k = j * 16 + t;
        g = fmaf(h1s[wave][k], W2s[k][cc], g);
    }
    g += __shfl_xor(g, 16);
    g += __shfl_xor(g, 32);
    g *= di;                           // h2' = dinv * h2
    float go = __shfl_xor(g, 1);
    if (lane < 16 && (cc & 1) == 0) {
        *(__half2*)&h2h[(size_t)node * 16 + cc] = __floats2half2_rn(g, go);
    }
}

// ---------------- fused agg2 + self-loop + b2 + log_softmax ----------------
__global__ __launch_bounds__(256) void k_agg2_final(const int* __restrict__ starts,
                                                    const int* __restrict__ ends,
                                                    const int* __restrict__ pack,
                                                    const float* __restrict__ dinv,
                                                    const __half* __restrict__ h2h,
                                                    const float* __restrict__ b2,
                                                    float* __restrict__ out) {
    const int tid = threadIdx.x;
    const int wave = tid >> 6;
    const int lane = tid & 63;
    const int node = blockIdx.x * 4 + wave;
    const int j = lane >> 3, cp = lane & 7;   // channels 2cp, 2cp+1

    const int s0 = starts[node], s1 = ends[node];
    float2 a0 = {0.f, 0.f}, a1 = {0.f, 0.f};
    int i = s0 + j;
    for (; i + 8 < s1; i += 16) {
        int p0 = pack[i], p1 = pack[i + 8];
        float2 f0 = __half22float2(*(const __half2*)(h2h + (size_t)p0 * 16 + 2 * cp));
        float2 f1 = __half22float2(*(const __half2*)(h2h + (size_t)p1 * 16 + 2 * cp));
        a0.x += f0.x; a0.y += f0.y;
        a1.x += f1.x; a1.y += f1.y;
    }
    for (; i < s1; i += 8) {
        int p = pack[i];
        float2 f = __half22float2(*(const __half2*)(h2h + (size_t)p * 16 + 2 * cp));
        a0.x += f.x; a0.y += f.y;
    }
    float2 z;
    z.x = a0.x + a1.x;
    z.y = a0.y + a1.y;
    z.x += __shfl_xor(z.x, 8);  z.y += __shfl_xor(z.y, 8);
    z.x += __shfl_xor(z.x, 16); z.y += __shfl_xor(z.y, 16);
    z.x += __shfl_xor(z.x, 32); z.y += __shfl_xor(z.y, 32);

    const float di = dinv[node];
    float2 sf = __half22float2(*(const __half2*)(h2h + (size_t)node * 16 + 2 * cp));
    z.x = (z.x + sf.x) * di + b2[2 * cp];
    z.y = (z.y + sf.y) * di + b2[2 * cp + 1];

    float m = fmaxf(z.x, z.y);
    m = fmaxf(m, __shfl_xor(m, 1, 8));
    m = fmaxf(m, __shfl_xor(m, 2, 8));
    m = fmaxf(m, __shfl_xor(m, 4, 8));
    float ex = __expf(z.x - m), ey = __expf(z.y - m);
    float s = ex + ey;
    s += __shfl_xor(s, 1, 8);
    s += __shfl_xor(s, 2, 8);
    s += __shfl_xor(s, 4, 8);
    float ls = logf(s);
    if (j == 0) {
        float2 o;
        o.x = z.x - m - ls;
        o.y = z.y - m - ls;
        *(float2*)&out[(size_t)node * 16 + 2 * cp] = o;
    }
}

extern "C" void kernel_launch(void* const* d_in, const int* in_sizes, int n_in,
                              void* d_out, int out_size, void* d_ws, size_t ws_size,
                              hipStream_t stream) {
    const float* x  = (const float*)d_in[0];
    const int* ei   = (const int*)d_in[1];
    const float* W1 = (const float*)d_in[2];
    const float* b1 = (const float*)d_in[3];
    const float* W2 = (const float*)d_in[4];
    const float* b2 = (const float*)d_in[5];
    const int* src = ei;
    const int* dst = ei + N_EDGES;

    // workspace layout (int units): 8192+196+100000+100000+100000 = 308388 (even) -> bpack/pack 8B ok,
    // hh byte offset = (308388 + 2*NB*CAP)*4 = 17289872, divisible by 8 -> uint2 loads aligned
    _Float16* Bfrag = (_Float16*)d_ws;                   // 16384 halves = 8192 ints
    int*    bcur    = (int*)d_ws + 8192;                 // NB
    int*    starts  = bcur + NB;                         // N
    int*    ends    = starts + N_NODES;                  // N
    float*  dinv    = (float*)(ends + N_NODES);          // N
    int*    bpack   = (int*)(dinv + N_NODES);            // NB*CAP
    int*    pack    = bpack + NB * CAP;                  // NB*CAP
    __half* hh      = (__half*)(pack + NB * CAP);        // N*64 half
    __half* h2h     = hh + (size_t)N_NODES * 64;         // N*16 half
    float*  out     = (float*)d_out;

    hipMemsetAsync(bcur, 0, NB * sizeof(int), stream);

    k_prepW1<<<64, 256, 0, stream>>>(W1, Bfrag);
    k_fill_bins<<<(N_EDGES + 4095) / 4096, 256, 0, stream>>>(src, dst, bcur, bpack);
    k_sort_bins<<<NB, 512, 0, stream>>>(bcur, bpack, pack, starts, ends, dinv);
    k_gemm1<<<(N_NODES + 63) / 64, 256, 0, stream>>>(x, Bfrag, dinv, hh);
    k_agg1_gemm2<<<N_NODES / 4, 256, 0, stream>>>(starts, ends, pack, dinv, hh, b1, W2, h2h);
    k_agg2_final<<<N_NODES / 4, 256, 0, stream>>>(starts, ends, pack, dinv, h2h, b2, out);
}